// Round 8
// baseline (91.935 us; speedup 1.0000x reference)
//
#include <hip/hip_runtime.h>
#include <hip/hip_bf16.h>
#include <math.h>

#define NUM_EXPERTS 64
#define HIDDEN      4096
#define T_TOKENS    16384   // B*S

using short8 = __attribute__((ext_vector_type(8))) short;   // 8 bf16
using f32x4  = __attribute__((ext_vector_type(4))) float;

// (f0,f1) -> packed bf16 hi (f0 in low 16) + packed bf16 lo residuals.
// Uses v_cvt_pk_bf16_f32 (RNE) via the HIP intrinsic; memcpy for bits
// (bit_cast rejects the non-trivially-copyable __hip_bfloat162).
__device__ __forceinline__ unsigned pack_pair(float f0, float f1, unsigned& lopk) {
    __hip_bfloat162 h2 = __float22bfloat162_rn(make_float2(f0, f1));
    unsigned hb; __builtin_memcpy(&hb, &h2, 4);
    float h0 = __builtin_bit_cast(float, hb << 16);
    float h1 = __builtin_bit_cast(float, hb & 0xffff0000u);
    __hip_bfloat162 l2 = __float22bfloat162_rn(make_float2(f0 - h0, f1 - h1));
    unsigned lb; __builtin_memcpy(&lb, &l2, 4);
    lopk = lb;
    return hb;
}
// 8 consecutive-k floats -> 16B hi plane + 16B lo plane
__device__ __forceinline__ void split8(const float4 a, const float4 b, uint4& hi, uint4& lo) {
    hi.x = pack_pair(a.x, a.y, lo.x);
    hi.y = pack_pair(a.z, a.w, lo.y);
    hi.z = pack_pair(b.x, b.y, lo.z);
    hi.w = pack_pair(b.z, b.w, lo.w);
}

#define MFMA(a, b, c) __builtin_amdgcn_mfma_f32_16x16x32_bf16((a), (b), (c), 0, 0, 0)

// ---- pre-kernel: split W [64][4096] f32 into fragment-ordered bf16 hi/lo planes.
// Fragment j = ((t*4 + nt)*64 + lane): lane holds W[e = nt*16 + (lane&15)]
// [k = t*32 + (lane>>4)*8 .. +8].  hi at ws[j*16], lo at ws + 512KB + j*16.
__global__ __launch_bounds__(256) void w_split_kernel(
    const float* __restrict__ W, unsigned char* __restrict__ ws)
{
    const int j  = blockIdx.x * 256 + threadIdx.x;   // 0..32767
    const int l  = j & 63;
    const int nt = (j >> 6) & 3;
    const int t  = j >> 8;
    const int e  = nt * 16 + (l & 15);
    const int k0 = t * 32 + ((l >> 4) & 3) * 8;
    const float* p = W + (size_t)e * HIDDEN + k0;
    float4 w0 = *reinterpret_cast<const float4*>(p);
    float4 w1 = *reinterpret_cast<const float4*>(p + 4);
    uint4 hi, lo;
    split8(w0, w1, hi, lo);
    *reinterpret_cast<uint4*>(ws + (size_t)j * 16)            = hi;
    *reinterpret_cast<uint4*>(ws + 524288 + (size_t)j * 16)   = lo;
}

// ---- main kernel: block = 16 tokens, 8 waves = K-split x8 (512 k each).
// Low-VGPR (<=128 -> 4 waves/SIMD): A dbuf 2+2 chunks, W dbuf 1-chunk
// lookahead. 8-way K combine via LDS, wave 0 does top-2.

// Load 2 consecutive A chunks (8 floats/lane each).
#define LOAD_A2(dst, t_) do {                                                  \
    const float* pA_ = aBase + (size_t)(t_) * 32;                              \
    dst[0][0] = *reinterpret_cast<const float4*>(pA_);                         \
    dst[0][1] = *reinterpret_cast<const float4*>(pA_ + 4);                     \
    dst[1][0] = *reinterpret_cast<const float4*>(pA_ + 32);                    \
    dst[1][1] = *reinterpret_cast<const float4*>(pA_ + 36);                    \
} while (0)

#define LOAD_W(dst, t_) do {                                                   \
    const unsigned char* pW_ = wsHi + (size_t)(tBase + (t_)) * 4096 + laneOff; \
    _Pragma("unroll")                                                          \
    for (int nt_ = 0; nt_ < 4; ++nt_) {                                        \
        dst[nt_]     = *reinterpret_cast<const uint4*>(pW_ + nt_ * 1024);      \
        dst[nt_ + 4] = *reinterpret_cast<const uint4*>(pW_ + 524288 + nt_ * 1024); \
    } } while (0)

// Compute one chunk from a 2-float4 A pair and one W buffer.
#define CHUNK1(a2_, wb_) do {                                                  \
    uint4 hi_, lo_;                                                            \
    split8(a2_[0], a2_[1], hi_, lo_);                                          \
    short8 ah_ = __builtin_bit_cast(short8, hi_);                              \
    short8 al_ = __builtin_bit_cast(short8, lo_);                              \
    _Pragma("unroll")                                                          \
    for (int nt_ = 0; nt_ < 4; ++nt_) {                                        \
        short8 wh_ = __builtin_bit_cast(short8, wb_[nt_]);                     \
        short8 wl_ = __builtin_bit_cast(short8, wb_[nt_ + 4]);                 \
        acc[nt_] = MFMA(ah_, wh_, acc[nt_]);                                   \
        acc[nt_] = MFMA(ah_, wl_, acc[nt_]);                                   \
        acc[nt_] = MFMA(al_, wh_, acc[nt_]);                                   \
    } } while (0)

__global__ __launch_bounds__(512, 4) void router_mfma_topk(
    const float* __restrict__ A,
    const unsigned char* __restrict__ wsHi,   // frag-ordered W hi; lo at +512KB
    float* __restrict__ out)
{
    __shared__ f32x4 part[8][4][64];          // 32 KB: [wave][nt][lane]

    const int tid  = threadIdx.x;
    const int lane = tid & 63;
    const int w    = tid >> 6;                // wave id = K-eighth (0..7)
    const int tok0 = blockIdx.x * 16;
    const int tBase = w * 16;                 // global chunk base (chunks of K=32)

    const float* aBase = A + (size_t)(tok0 + (lane & 15)) * HIDDEN
                           + w * 512 + ((lane >> 4) & 3) * 8;
    const int laneOff = lane * 16;

    f32x4 acc[4];
#pragma unroll
    for (int nt = 0; nt < 4; ++nt) acc[nt] = (f32x4){0.f, 0.f, 0.f, 0.f};

    float4 a0[2][2], a1[2][2];   // A ping-pong: 2 chunks each
    uint4  wX[8], wY[8];         // W double buffer (hi 0..3, lo 4..7)

    LOAD_W(wX, 0);
    LOAD_A2(a0, 0);

#pragma unroll
    for (int g = 0; g < 4; ++g) {             // 4 chunks per iteration
        const int t = g * 4;
        LOAD_W(wY, t + 1);
        LOAD_A2(a1, t + 2);
        CHUNK1(a0[0], wX);                    // chunk t
        LOAD_W(wX, t + 2);
        CHUNK1(a0[1], wY);                    // chunk t+1
        LOAD_W(wY, t + 3);
        if (g < 3) LOAD_A2(a0, t + 4);
        CHUNK1(a1[0], wX);                    // chunk t+2
        if (g < 3) LOAD_W(wX, t + 4);
        CHUNK1(a1[1], wY);                    // chunk t+3
    }

    // ---- combine K-eighths via LDS ----
#pragma unroll
    for (int nt = 0; nt < 4; ++nt) part[w][nt][lane] = acc[nt];
    __syncthreads();

    if (w == 0) {
#pragma unroll
        for (int nt = 0; nt < 4; ++nt) {
#pragma unroll
            for (int q = 1; q < 8; ++q) acc[nt] = acc[nt] + part[q][nt][lane];
        }

        // ---- all-register top-2: lane holds rows (lane>>4)*4+r, col nt*16+(lane&15)
        const int eBase = lane & 15;
#pragma unroll
        for (int r = 0; r < 4; ++r) {
            float b1 = acc[0][r]; int i1 = eBase;
            float b2 = -INFINITY; int i2 = 0;
#pragma unroll
            for (int nt = 1; nt < 4; ++nt) {
                float v = acc[nt][r];
                int   e = nt * 16 + eBase;
                if (v > b1)      { b2 = b1; i2 = i1; b1 = v; i1 = e; }
                else if (v > b2) { b2 = v;  i2 = e; }
            }
#pragma unroll
            for (int m = 1; m <= 8; m <<= 1) {
                float o1 = __shfl_xor(b1, m); int oi1 = __shfl_xor(i1, m);
                float o2 = __shfl_xor(b2, m); int oi2 = __shfl_xor(i2, m);
                float n1, c, n2; int ni1, ci, ni2;
                if (o1 > b1 || (o1 == b1 && oi1 < i1)) { n1 = o1; ni1 = oi1; c = b1; ci = i1; }
                else                                   { n1 = b1; ni1 = i1;  c = o1; ci = oi1; }
                if (b2 > o2 || (b2 == o2 && i2 < oi2)) { n2 = b2; ni2 = i2; }
                else                                   { n2 = o2; ni2 = oi2; }
                if (c > n2 || (c == n2 && ci < ni2))   { n2 = c;  ni2 = ci; }
                b1 = n1; i1 = ni1; b2 = n2; i2 = ni2;
            }
            if ((lane & 15) == 0) {
                const int tok = tok0 + (lane >> 4) * 4 + r;
                out[(size_t)tok * 2 + 0] = b1;
                out[(size_t)tok * 2 + 1] = b2;
                out[(size_t)2 * T_TOKENS + (size_t)tok * 2 + 0] = (float)i1;
                out[(size_t)2 * T_TOKENS + (size_t)tok * 2 + 1] = (float)i2;
            }
        }
    }
}

extern "C" void kernel_launch(void* const* d_in, const int* in_sizes, int n_in,
                              void* d_out, int out_size, void* d_ws, size_t ws_size,
                              hipStream_t stream) {
    const float* A = (const float*)d_in[0];   // hidden_states fp32 [16384,4096]
    const float* W = (const float*)d_in[1];   // W fp32 [64,4096]
    float* out = (float*)d_out;
    unsigned char* ws = (unsigned char*)d_ws; // 1 MB used (hi 512K + lo 512K)

    w_split_kernel<<<dim3(128), dim3(256), 0, stream>>>(W, ws);
    router_mfma_topk<<<dim3(T_TOKENS / 16), dim3(512), 0, stream>>>(A, ws, out);
}

// Round 9
// 69.137 us; speedup vs baseline: 1.3298x; 1.3298x over previous
//
#include <hip/hip_runtime.h>
#include <hip/hip_bf16.h>
#include <math.h>

#define NUM_EXPERTS 64
#define HIDDEN      4096
#define T_TOKENS    16384   // B*S

using short8 = __attribute__((ext_vector_type(8))) short;   // 8 bf16
using f32x4  = __attribute__((ext_vector_type(4))) float;

// (f0,f1) -> packed bf16 hi (f0 in low 16) + packed bf16 lo residuals.
// v_cvt_pk_bf16_f32 (RNE) via HIP intrinsic; memcpy for bits (bit_cast
// rejects the non-trivially-copyable __hip_bfloat162).
__device__ __forceinline__ unsigned pack_pair(float f0, float f1, unsigned& lopk) {
    __hip_bfloat162 h2 = __float22bfloat162_rn(make_float2(f0, f1));
    unsigned hb; __builtin_memcpy(&hb, &h2, 4);
    float h0 = __builtin_bit_cast(float, hb << 16);
    float h1 = __builtin_bit_cast(float, hb & 0xffff0000u);
    __hip_bfloat162 l2 = __float22bfloat162_rn(make_float2(f0 - h0, f1 - h1));
    unsigned lb; __builtin_memcpy(&lb, &l2, 4);
    lopk = lb;
    return hb;
}
// 8 consecutive-k floats -> 16B hi plane + 16B lo plane
__device__ __forceinline__ void split8(const float4 a, const float4 b, uint4& hi, uint4& lo) {
    hi.x = pack_pair(a.x, a.y, lo.x);
    hi.y = pack_pair(a.z, a.w, lo.y);
    hi.z = pack_pair(b.x, b.y, lo.z);
    hi.w = pack_pair(b.z, b.w, lo.w);
}

#define MFMA(a, b, c) __builtin_amdgcn_mfma_f32_16x16x32_bf16((a), (b), (c), 0, 0, 0)

// ---- pre-kernel: split W [64][4096] f32 into fragment-ordered bf16 hi/lo planes.
// Fragment j = ((t*4 + nt)*64 + lane): lane holds W[e = nt*16 + (lane&15)]
// [k = t*32 + (lane>>4)*8 .. +8].  hi at ws[j*16], lo at ws + 512KB + j*16.
__global__ __launch_bounds__(256) void w_split_kernel(
    const float* __restrict__ W, unsigned char* __restrict__ ws)
{
    const int j  = blockIdx.x * 256 + threadIdx.x;   // 0..32767
    const int l  = j & 63;
    const int nt = (j >> 6) & 3;
    const int t  = j >> 8;
    const int e  = nt * 16 + (l & 15);
    const int k0 = t * 32 + ((l >> 4) & 3) * 8;
    const float* p = W + (size_t)e * HIDDEN + k0;
    float4 w0 = *reinterpret_cast<const float4*>(p);
    float4 w1 = *reinterpret_cast<const float4*>(p + 4);
    uint4 hi, lo;
    split8(w0, w1, hi, lo);
    *reinterpret_cast<uint4*>(ws + (size_t)j * 16)            = hi;
    *reinterpret_cast<uint4*>(ws + 524288 + (size_t)j * 16)   = lo;
}

// ---- main kernel: block = 64 tokens, 8 waves = K-split x8 (512 k each).
// Each wave computes the FULL 64x64 output tile over its K-eighth
// (4 M-tiles x 4 N-tiles, 16 f32x4 accs) -> W re-read amplification drops
// from 1024x (16-token tile) to 256x: W L2 traffic 1 GB -> 256 MB.

// Load one chunk of A for all 4 M-tiles (8 floats/lane per tile).
#define LOAD_A4(dst, t_) do {                                                  \
    const float* pA_ = aBase + (size_t)(t_) * 32;                              \
    _Pragma("unroll")                                                          \
    for (int mt_ = 0; mt_ < 4; ++mt_) {                                        \
        dst[mt_][0] = *reinterpret_cast<const float4*>(pA_ + (size_t)mt_ * 16 * HIDDEN);     \
        dst[mt_][1] = *reinterpret_cast<const float4*>(pA_ + (size_t)mt_ * 16 * HIDDEN + 4); \
    } } while (0)

#define LOAD_W(dst, t_) do {                                                   \
    const unsigned char* pW_ = wsHi + (size_t)(tBase + (t_)) * 4096 + laneOff; \
    _Pragma("unroll")                                                          \
    for (int nt_ = 0; nt_ < 4; ++nt_) {                                        \
        dst[nt_]     = *reinterpret_cast<const uint4*>(pW_ + nt_ * 1024);      \
        dst[nt_ + 4] = *reinterpret_cast<const uint4*>(pW_ + 524288 + nt_ * 1024); \
    } } while (0)

// One K=32 chunk: 4 M-tiles x 4 N-tiles x 3 split-terms = 48 MFMA.
#define CHUNK4(ab_, wb_) do {                                                  \
    _Pragma("unroll")                                                          \
    for (int mt_ = 0; mt_ < 4; ++mt_) {                                        \
        uint4 hi_, lo_;                                                        \
        split8(ab_[mt_][0], ab_[mt_][1], hi_, lo_);                            \
        short8 ah_ = __builtin_bit_cast(short8, hi_);                          \
        short8 al_ = __builtin_bit_cast(short8, lo_);                          \
        _Pragma("unroll")                                                      \
        for (int nt_ = 0; nt_ < 4; ++nt_) {                                    \
            short8 wh_ = __builtin_bit_cast(short8, wb_[nt_]);                 \
            short8 wl_ = __builtin_bit_cast(short8, wb_[nt_ + 4]);             \
            acc[mt_][nt_] = MFMA(ah_, wh_, acc[mt_][nt_]);                     \
            acc[mt_][nt_] = MFMA(ah_, wl_, acc[mt_][nt_]);                     \
            acc[mt_][nt_] = MFMA(al_, wh_, acc[mt_][nt_]);                     \
        } } } while (0)

__global__ __launch_bounds__(512, 2) void router_mfma_topk(
    const float* __restrict__ A,
    const unsigned char* __restrict__ wsHi,   // frag-ordered W hi; lo at +512KB
    float* __restrict__ out)
{
    __shared__ f32x4 part[4][4][4][64];       // 64 KB: [q][mt][nt][lane]

    const int tid  = threadIdx.x;
    const int lane = tid & 63;
    const int w    = tid >> 6;                // wave id = K-eighth (0..7)
    const int tok0 = blockIdx.x * 64;
    const int tBase = w * 16;                 // chunk base (chunks of K=32)

    const float* aBase = A + (size_t)(tok0 + (lane & 15)) * HIDDEN
                           + w * 512 + ((lane >> 4) & 3) * 8;
    const int laneOff = lane * 16;

    f32x4 acc[4][4];                          // [mt][nt]
#pragma unroll
    for (int mt = 0; mt < 4; ++mt)
#pragma unroll
        for (int nt = 0; nt < 4; ++nt) acc[mt][nt] = (f32x4){0.f, 0.f, 0.f, 0.f};

    float4 aC[4][2], aN[4][2];   // A ping-pong (1 chunk each, 4 M-tiles)
    uint4  wX[8], wY[8];         // W ping-pong (hi 0..3, lo 4..7)

    LOAD_W(wX, 0);
    LOAD_A4(aC, 0);

#pragma unroll
    for (int t = 0; t < 16; t += 2) {
        LOAD_W(wY, t + 1);
        LOAD_A4(aN, t + 1);
        CHUNK4(aC, wX);                       // chunk t
        if (t + 2 < 16) { LOAD_W(wX, t + 2); LOAD_A4(aC, t + 2); }
        CHUNK4(aN, wY);                       // chunk t+1
    }

    // ---- combine 8 K-eighths: waves 0-3 write, waves 4-7 RMW-add, then
    // wave w<4 sums q=0..3 for its M-tile and does the top-2.
    if (w < 4) {
#pragma unroll
        for (int mt = 0; mt < 4; ++mt)
#pragma unroll
            for (int nt = 0; nt < 4; ++nt) part[w][mt][nt][lane] = acc[mt][nt];
    }
    __syncthreads();
    if (w >= 4) {
#pragma unroll
        for (int mt = 0; mt < 4; ++mt)
#pragma unroll
            for (int nt = 0; nt < 4; ++nt)
                part[w - 4][mt][nt][lane] = part[w - 4][mt][nt][lane] + acc[mt][nt];
    }
    __syncthreads();

    if (w < 4) {
        // sum the 4 combined partials for M-tile mt = w
        f32x4 s[4];
#pragma unroll
        for (int nt = 0; nt < 4; ++nt) {
            s[nt] = part[0][w][nt][lane];
#pragma unroll
            for (int q = 1; q < 4; ++q) s[nt] = s[nt] + part[q][w][nt][lane];
        }

        // ---- all-register top-2: lane holds rows (lane>>4)*4+r, col nt*16+(lane&15)
        const int eBase = lane & 15;
#pragma unroll
        for (int r = 0; r < 4; ++r) {
            float b1 = s[0][r]; int i1 = eBase;
            float b2 = -INFINITY; int i2 = 0;
#pragma unroll
            for (int nt = 1; nt < 4; ++nt) {
                float v = s[nt][r];
                int   e = nt * 16 + eBase;
                if (v > b1)      { b2 = b1; i2 = i1; b1 = v; i1 = e; }
                else if (v > b2) { b2 = v;  i2 = e; }
            }
#pragma unroll
            for (int m = 1; m <= 8; m <<= 1) {
                float o1 = __shfl_xor(b1, m); int oi1 = __shfl_xor(i1, m);
                float o2 = __shfl_xor(b2, m); int oi2 = __shfl_xor(i2, m);
                float n1, c, n2; int ni1, ci, ni2;
                if (o1 > b1 || (o1 == b1 && oi1 < i1)) { n1 = o1; ni1 = oi1; c = b1; ci = i1; }
                else                                   { n1 = b1; ni1 = i1;  c = o1; ci = oi1; }
                if (b2 > o2 || (b2 == o2 && i2 < oi2)) { n2 = b2; ni2 = i2; }
                else                                   { n2 = o2; ni2 = oi2; }
                if (c > n2 || (c == n2 && ci < ni2))   { n2 = c;  ni2 = ci; }
                b1 = n1; i1 = ni1; b2 = n2; i2 = ni2;
            }
            if ((lane & 15) == 0) {
                const int tok = tok0 + w * 16 + (lane >> 4) * 4 + r;
                out[(size_t)tok * 2 + 0] = b1;
                out[(size_t)tok * 2 + 1] = b2;
                out[(size_t)2 * T_TOKENS + (size_t)tok * 2 + 0] = (float)i1;
                out[(size_t)2 * T_TOKENS + (size_t)tok * 2 + 1] = (float)i2;
            }
        }
    }
}

extern "C" void kernel_launch(void* const* d_in, const int* in_sizes, int n_in,
                              void* d_out, int out_size, void* d_ws, size_t ws_size,
                              hipStream_t stream) {
    const float* A = (const float*)d_in[0];   // hidden_states fp32 [16384,4096]
    const float* W = (const float*)d_in[1];   // W fp32 [64,4096]
    float* out = (float*)d_out;
    unsigned char* ws = (unsigned char*)d_ws; // 1 MB used (hi 512K + lo 512K)

    w_split_kernel<<<dim3(128), dim3(256), 0, stream>>>(W, ws);
    router_mfma_topk<<<dim3(T_TOKENS / 64), dim3(512), 0, stream>>>(A, ws, out);
}